// Round 7
// baseline (177.240 us; speedup 1.0000x reference)
//
#include <hip/hip_runtime.h>
#include <math.h>

// Problem constants (B=1)
#define HH 16
#define WW 16
#define DD 16
#define LL 4096          // H*W*Dd
#define CC 48            // d_model
#define DIN 48           // d_inner
#define NN 16            // d_state
#define RR 3             // dt_rank
#define KK 8             // scan directions
#define KD 384           // K*DIN
#define NCH 64           // chunks along L
#define CHL 64           // chunk length

// Multi-stride LDS pad for a 16x16x16 volume: conflict-free at strides
// 1 (dd), 16 (w: 17 mod 32), 256 (h: 273 mod 32 = 17). Max idx 4365.
#define OL(s) ((s) + ((s) >> 4) + ((s) >> 8))

// DPP-based 16-lane (within-row) sum: xor1, xor2 via quad_perm; then
// row_ror:4 + row_ror:8 complete the 16-lane reduction. Pure VALU, no LDS.
__device__ __forceinline__ float dpp_add(float x, const int ctrl_tag) {
    int xi = __float_as_int(x);
    int yi;
    switch (ctrl_tag) {
        case 0: yi = __builtin_amdgcn_update_dpp(0, xi, 0xB1, 0xF, 0xF, true); break; // quad_perm [1,0,3,2]
        case 1: yi = __builtin_amdgcn_update_dpp(0, xi, 0x4E, 0xF, 0xF, true); break; // quad_perm [2,3,0,1]
        case 2: yi = __builtin_amdgcn_update_dpp(0, xi, 0x124, 0xF, 0xF, true); break; // row_ror:4
        default: yi = __builtin_amdgcn_update_dpp(0, xi, 0x128, 0xF, 0xF, true); break; // row_ror:8
    }
    return x + __int_as_float(yi);
}
__device__ __forceinline__ float row16_sum(float p) {
    p = dpp_add(p, 0);
    p = dpp_add(p, 1);
    p = dpp_add(p, 2);
    p = dpp_add(p, 3);
    return p;
}

// scan-index -> natural-site map
__device__ __forceinline__ int perm_src(int ll, int kperm) {
    int a = ll >> 8, b2 = (ll >> 4) & 15, c2 = ll & 15;
    switch (kperm) {
        case 0:  return ll;
        case 1:  return b2 * 256 + a * 16 + c2;
        case 2:  return c2 * 256 + b2 * 16 + a;
        default: return a * 256 + c2 * 16 + b2;
    }
}

// ---------------- Kernel 1: in_proj  xz[l,e] = sum_c x[l,c]*W[e,c] ----------
// Also zeroes the lookback sync slots (2 kernel boundaries before k_scanAB).
__global__ __launch_bounds__(256) void k_inproj(const float* __restrict__ x,
                                                const float* __restrict__ W,
                                                float* __restrict__ xm,
                                                float* __restrict__ z,
                                                int* __restrict__ sync) {
    int tid = blockIdx.x * 256 + threadIdx.x;          // l*96 + e
    if (blockIdx.x == 0 && threadIdx.x < 64) {
#pragma unroll
        for (int r = 0; r < 9; ++r) {
            int i = r * 64 + threadIdx.x;
            if (i < 513) sync[i] = 0;                  // counter + 512 flags
        }
    }
    if (tid >= LL * 96) return;
    int e = tid % 96, l = tid / 96;
    const float4* xr = (const float4*)(x + l * CC);
    const float4* wr = (const float4*)(W + e * CC);
    float acc = 0.f;
#pragma unroll
    for (int c4 = 0; c4 < CC / 4; ++c4) {
        float4 a = xr[c4], b = wr[c4];
        acc += a.x * b.x + a.y * b.y + a.z * b.z + a.w * b.w;
    }
    if (e < DIN) xm[e * LL + l] = acc;
    else         z[l * DIN + (e - DIN)] = acc;
}

// ---- Kernel 2: depthwise 3x3x3 conv + bias + SiLU, emitting 4 PRE-PERMUTED
// copies xcp[p][d][l']. Block per channel d; whole 16^3 volume in padded LDS.
__global__ __launch_bounds__(1024) void k_conv(const float* __restrict__ xm,
                                               const float* __restrict__ cw,
                                               const float* __restrict__ cb,
                                               float* __restrict__ xcp) {
    int d = blockIdx.x;
    int tid = threadIdx.x;
    __shared__ float xin[4366];
    __shared__ float xout[4366];
    {
        float4 v = ((const float4*)(xm + (size_t)d * LL))[tid];
        int o = OL(tid * 4);                           // 4j stays in-group
        xin[o] = v.x; xin[o + 1] = v.y; xin[o + 2] = v.z; xin[o + 3] = v.w;
    }
    __syncthreads();
    const float* wp = cw + d * 27;
    float bias = cb[d];
#pragma unroll
    for (int j = 0; j < 4; ++j) {
        int s = tid * 4 + j;
        int dd = s & 15, w = (s >> 4) & 15, h = s >> 8;
        float acc = 0.f;
#pragma unroll
        for (int i = -1; i <= 1; ++i) {
            int hh = h + i; if (hh < 0 || hh > 15) continue;
#pragma unroll
            for (int jj = -1; jj <= 1; ++jj) {
                int ww2 = w + jj; if (ww2 < 0 || ww2 > 15) continue;
#pragma unroll
                for (int q = -1; q <= 1; ++q) {
                    int dd2 = dd + q; if (dd2 < 0 || dd2 > 15) continue;
                    acc += wp[(i + 1) * 9 + (jj + 1) * 3 + (q + 1)]
                         * xin[OL(hh * 256 + ww2 * 16 + dd2)];
                }
            }
        }
        acc += bias;
        xout[OL(s)] = acc / (1.f + __expf(-acc));      // SiLU
    }
    __syncthreads();
#pragma unroll
    for (int p = 0; p < 4; ++p) {
        float4 v;
#pragma unroll
        for (int j = 0; j < 4; ++j) {
            int lp = tid * 4 + j;
            (&v.x)[j] = xout[OL(perm_src(lp, p))];
        }
        ((float4*)(xcp + ((size_t)p * DIN + d) * LL))[tid] = v;
    }
}

// ---- Shared front-end: coalesced stage from xcp + x_proj GEMM + dt_proj ----
__device__ __forceinline__ void frontend(const float* __restrict__ xcp,
                                         const float* __restrict__ xpw,
                                         const float* __restrict__ dtw,
                                         const float* __restrict__ dtb,
                                         int k, int l0, int tid,
                                         float* xt, float* xd, float2* ud) {
    int kperm = k & 3, krev = k & 4;
    // coalesced stage from the pre-permuted copy (1 float4/thread)
    {
        int d = tid >> 4, q = tid & 15;
        const float* row = xcp + ((size_t)kperm * DIN + d) * LL;
        if (!krev) {
            float4 v = ((const float4*)(row + l0))[q];
            xt[d * 68 + q * 4 + 0] = v.x; xt[d * 68 + q * 4 + 1] = v.y;
            xt[d * 68 + q * 4 + 2] = v.z; xt[d * 68 + q * 4 + 3] = v.w;
        } else {
            float4 v = ((const float4*)(row + (LL - CHL - l0)))[15 - q];
            xt[d * 68 + q * 4 + 3] = v.x; xt[d * 68 + q * 4 + 2] = v.y;
            xt[d * 68 + q * 4 + 1] = v.z; xt[d * 68 + q * 4 + 0] = v.w;
        }
    }
    __syncthreads();
    // GEMM: x_dbl[cc][l] = sum_d u[d][l] * xpw[k][cc][d]
    if (tid < 560) {
        int cc = tid % 35, l4 = tid / 35;
        const float* wr = xpw + (k * 35 + cc) * DIN;   // L1-broadcast
        float4 acc = {0.f, 0.f, 0.f, 0.f};
#pragma unroll
        for (int d2 = 0; d2 < 48; ++d2) {
            float4 v = ((const float4*)(xt + d2 * 68))[l4];
            float w = wr[d2];
            acc.x += v.x * w; acc.y += v.y * w; acc.z += v.z * w; acc.w += v.w * w;
        }
        float* o = xd + cc * 65 + l4 * 4;
        o[0] = acc.x; o[1] = acc.y; o[2] = acc.z; o[3] = acc.w;
    }
    __syncthreads();
    // delta = softplus(dts @ dtw + bias); pack (u,delta) to LDS
#pragma unroll
    for (int r = 0; r < 4; ++r) {
        int item = r * 768 + tid;
        int d2 = item >> 6, l = item & 63;
        int gd = k * DIN + d2;
        float v = xd[l] * dtw[gd * 3] + xd[65 + l] * dtw[gd * 3 + 1]
                + xd[130 + l] * dtw[gd * 3 + 2] + dtb[gd];
        float sp = (v > 20.f) ? v : log1pf(__expf(v));
        ud[d2 * 68 + l] = make_float2(xt[d2 * 68 + l], sp);
    }
    __syncthreads();
}

// ---- Kernel 3: SINGLE-PASS scan with decoupled lookback. -------------------
// Block = (k, chunk) via atomic ticket (deadlock-free: ordinal j only waits
// on ordinals < j, grabbed by already-running blocks; all 512 blocks are
// co-resident anyway at 2/CU). Frontend runs ONCE; phase-1 summary is
// published with device-scope release; predecessors' summaries are combined
// locally after relaxed flag polls + one acquire fence (cache inv — needed
// because the workspace poison fill can leave stale phf lines in this XCD's
// L2); phase 3 then re-scans straight from the LDS tiles.
__global__ __launch_bounds__(768) void k_scanAB(
        const float* __restrict__ xcp, const float* __restrict__ xpw,
        const float* __restrict__ dtw, const float* __restrict__ dtb,
        const float* __restrict__ A_logs, const float* __restrict__ Ds,
        float2* __restrict__ phf, int* __restrict__ sync,
        float* __restrict__ y2) {
    __shared__ float  xt[48 * 68];                     // u tile, then y tile
    __shared__ float  xd[35 * 65];
    __shared__ float2 ud[48 * 68];
    __shared__ int s_bid;
    int tid = threadIdx.x;
    if (tid == 0) s_bid = atomicAdd(&sync[0], 1);      // ticket
    __syncthreads();
    int bid = s_bid;
    int k = bid >> 6, c = bid & (NCH - 1);
    int l0 = c * CHL;
    frontend(xcp, xpw, dtw, dtb, k, l0, tid, xt, xd, ud);
    int d = tid >> 4, n = tid & 15;
    int gid = k * DIN + d;
    float A = -__expf(A_logs[gid * NN + n]);
    float Dv = Ds[gid];
    // --- phase 1: local chunk scan (h from 0)
    float h1 = 0.f, pa = 1.f;
#pragma unroll 8
    for (int i = 0; i < CHL; ++i) {
        float2 uv = ud[d * 68 + i];
        float Bv = xd[(3 + n) * 65 + i];
        float dA = __expf(uv.y * A);
        h1 = h1 * dA + uv.y * uv.x * Bv;
        pa *= dA;
    }
    // --- publish: stores drained by the barrier (vmcnt(0) before s_barrier),
    // then one L2-writeback fence + release flag from tid 0.
    phf[(size_t)bid * 768 + tid] = make_float2(pa, h1);
    __syncthreads();
    if (tid == 0) {
        __threadfence();
        __hip_atomic_store(&sync[1 + bid], 1, __ATOMIC_RELEASE,
                           __HIP_MEMORY_SCOPE_AGENT);
    }
    // --- poll predecessor flags (thread t watches chunk t of this k)
    if (tid < c) {
        while (__hip_atomic_load(&sync[1 + (k << 6) + tid], __ATOMIC_RELAXED,
                                 __HIP_MEMORY_SCOPE_AGENT) == 0) {
            __builtin_amdgcn_s_sleep(2);
        }
    }
    __syncthreads();
    if (tid == 0) __threadfence();                     // acquire: inv L1/L2
    __syncthreads();
    // --- seed = exclusive combine of chunks [0,c); 8 independent loads/group
    float h = 0.f;
    {
        const float2* pp = phf + ((size_t)(k << 6)) * 768 + tid;
        int cc = 0;
        for (; cc + 8 <= c; cc += 8) {
            float2 v0 = pp[(size_t)(cc + 0) * 768];
            float2 v1 = pp[(size_t)(cc + 1) * 768];
            float2 v2 = pp[(size_t)(cc + 2) * 768];
            float2 v3 = pp[(size_t)(cc + 3) * 768];
            float2 v4 = pp[(size_t)(cc + 4) * 768];
            float2 v5 = pp[(size_t)(cc + 5) * 768];
            float2 v6 = pp[(size_t)(cc + 6) * 768];
            float2 v7 = pp[(size_t)(cc + 7) * 768];
            h = h * v0.x + v0.y; h = h * v1.x + v1.y;
            h = h * v2.x + v2.y; h = h * v3.x + v3.y;
            h = h * v4.x + v4.y; h = h * v5.x + v5.y;
            h = h * v6.x + v6.y; h = h * v7.x + v7.y;
        }
        for (; cc < c; ++cc) {
            float2 v = pp[(size_t)cc * 768];
            h = h * v.x + v.y;
        }
    }
    // --- phase 3: seeded re-scan, fully LDS-fed; y tile reuses xt
#pragma unroll 8
    for (int i = 0; i < CHL; ++i) {
        float2 uv = ud[d * 68 + i];
        float Bv = xd[(3 + n) * 65 + i];
        float Cv = xd[(19 + n) * 65 + i];
        float dA = __expf(uv.y * A);
        h = h * dA + uv.y * uv.x * Bv;
        float p = row16_sum(h * Cv);                   // pure-VALU 16-lane sum
        if (n == 0) xt[d * 68 + i] = p + Dv * uv.x;
    }
    __syncthreads();
    // --- de-permuted store: y2[s][k*48..+47], 192B contiguous per (l)
    {
        int g = tid >> 6, l = tid & 63;                // g: 0..11
        int lg = l0 + l;
        int ll = (k & 4) ? (LL - 1 - lg) : lg;
        int sp = perm_src(ll, k & 3);
        float4 v;
#pragma unroll
        for (int j = 0; j < 4; ++j) (&v.x)[j] = xt[(g * 4 + j) * 68 + l];
        ((float4*)(y2 + (size_t)sp * KD + k * DIN))[g] = v;
    }
}

// ---- Kernel 4: sum dirs + LayerNorm + gate + out_proj. Wave per s. ---------
__global__ __launch_bounds__(256) void k_final2(const float* __restrict__ y2,
                                                const float* __restrict__ z,
                                                const float* __restrict__ nw,
                                                const float* __restrict__ nb,
                                                const float* __restrict__ opw,
                                                float* __restrict__ out) {
    int wv = threadIdx.x >> 6, lane = threadIdx.x & 63;
    int s = blockIdx.x * 4 + wv;
    __shared__ float g[4][DIN];
    float val = 0.f;
    if (lane < DIN) {
        const float* yp = y2 + (size_t)s * KD + lane;
#pragma unroll
        for (int k = 0; k < KK; ++k) val += yp[k * DIN];
    }
    float m = val;
#pragma unroll
    for (int o = 32; o >= 1; o >>= 1) m += __shfl_xor(m, o, 64);
    m *= (1.f / 48.f);
    float dv = (lane < DIN) ? (val - m) : 0.f;
    float v2 = dv * dv;
#pragma unroll
    for (int o = 32; o >= 1; o >>= 1) v2 += __shfl_xor(v2, o, 64);
    v2 *= (1.f / 48.f);
    float inv = rsqrtf(v2 + 1e-5f);
    if (lane < DIN) {
        float yn = dv * inv * nw[lane] + nb[lane];
        float zz = z[s * DIN + lane];
        g[wv][lane] = yn * (zz / (1.f + __expf(-zz)));
    }
    __syncthreads();
    if (lane < DIN) {
        const float* wr = opw + lane * DIN;            // out_proj_w[c, e]
        float acc = 0.f;
#pragma unroll
        for (int e = 0; e < DIN; ++e) acc += g[wv][e] * wr[e];
        out[s * CC + lane] = acc;
    }
}

extern "C" void kernel_launch(void* const* d_in, const int* in_sizes, int n_in,
                              void* d_out, int out_size, void* d_ws, size_t ws_size,
                              hipStream_t stream) {
    const float* x      = (const float*)d_in[0];
    const float* ipw    = (const float*)d_in[1];
    const float* cw     = (const float*)d_in[2];
    const float* cb     = (const float*)d_in[3];
    const float* xpw    = (const float*)d_in[4];
    const float* dtw    = (const float*)d_in[5];
    const float* dtb    = (const float*)d_in[6];
    const float* A_logs = (const float*)d_in[7];
    const float* Ds     = (const float*)d_in[8];
    const float* nw     = (const float*)d_in[9];
    const float* nb     = (const float*)d_in[10];
    const float* opw    = (const float*)d_in[11];
    float* out = (float*)d_out;

    float* ws    = (float*)d_ws;
    float* xm    = ws;                                 // DIN*LL
    float* z     = xm + DIN * LL;                      // LL*DIN
    float* xcp   = z + LL * DIN;                       // 4*DIN*LL (perm copies)
    float* y2    = xcp + (size_t)4 * DIN * LL;         // LL*KD (s-major)
    float* phf_f = y2 + (size_t)LL * KD;               // 512*768 float2
    int*   sync  = (int*)(phf_f + (size_t)2 * 512 * 768); // counter + 512 flags

    k_inproj<<<(LL * 96 + 255) / 256, 256, 0, stream>>>(x, ipw, xm, z, sync);
    k_conv<<<DIN, 1024, 0, stream>>>(xm, cw, cb, xcp);
    k_scanAB<<<KK * NCH, 768, 0, stream>>>(xcp, xpw, dtw, dtb, A_logs, Ds,
                                           (float2*)phf_f, sync, y2);
    k_final2<<<LL / 4, 256, 0, stream>>>(y2, z, nw, nb, opw, out);
}

// Round 8
// 149.113 us; speedup vs baseline: 1.1886x; 1.1886x over previous
//
#include <hip/hip_runtime.h>
#include <math.h>

// Problem constants (B=1)
#define HH 16
#define WW 16
#define DD 16
#define LL 4096          // H*W*Dd
#define CC 48            // d_model
#define DIN 48           // d_inner
#define NN 16            // d_state
#define RR 3             // dt_rank
#define KK 8             // scan directions
#define KD 384           // K*DIN
#define NCH 64           // chunks along L
#define CHL 64           // chunk length

// Multi-stride LDS pad for a 16x16x16 volume: conflict-free at strides
// 1 (dd), 16 (w: 17 mod 32), 256 (h: 273 mod 32 = 17). Max idx 4365.
#define OL(s) ((s) + ((s) >> 4) + ((s) >> 8))

// DPP-based 16-lane (within-row) sum: xor1, xor2 via quad_perm; then
// row_ror:4 + row_ror:8 complete the 16-lane reduction. Pure VALU, no LDS.
__device__ __forceinline__ float dpp_add(float x, const int ctrl_tag) {
    int xi = __float_as_int(x);
    int yi;
    switch (ctrl_tag) {
        case 0: yi = __builtin_amdgcn_update_dpp(0, xi, 0xB1, 0xF, 0xF, true); break; // quad_perm [1,0,3,2]
        case 1: yi = __builtin_amdgcn_update_dpp(0, xi, 0x4E, 0xF, 0xF, true); break; // quad_perm [2,3,0,1]
        case 2: yi = __builtin_amdgcn_update_dpp(0, xi, 0x124, 0xF, 0xF, true); break; // row_ror:4
        default: yi = __builtin_amdgcn_update_dpp(0, xi, 0x128, 0xF, 0xF, true); break; // row_ror:8
    }
    return x + __int_as_float(yi);
}
__device__ __forceinline__ float row16_sum(float p) {
    p = dpp_add(p, 0);
    p = dpp_add(p, 1);
    p = dpp_add(p, 2);
    p = dpp_add(p, 3);
    return p;
}

// scan-index -> natural-site map
__device__ __forceinline__ int perm_src(int ll, int kperm) {
    int a = ll >> 8, b2 = (ll >> 4) & 15, c2 = ll & 15;
    switch (kperm) {
        case 0:  return ll;
        case 1:  return b2 * 256 + a * 16 + c2;
        case 2:  return c2 * 256 + b2 * 16 + a;
        default: return a * 256 + c2 * 16 + b2;
    }
}

// ---------------- Kernel 1: in_proj  xz[l,e] = sum_c x[l,c]*W[e,c] ----------
__global__ __launch_bounds__(256) void k_inproj(const float* __restrict__ x,
                                                const float* __restrict__ W,
                                                float* __restrict__ xm,
                                                float* __restrict__ z) {
    int tid = blockIdx.x * 256 + threadIdx.x;          // l*96 + e
    if (tid >= LL * 96) return;
    int e = tid % 96, l = tid / 96;
    const float4* xr = (const float4*)(x + l * CC);
    const float4* wr = (const float4*)(W + e * CC);
    float acc = 0.f;
#pragma unroll
    for (int c4 = 0; c4 < CC / 4; ++c4) {
        float4 a = xr[c4], b = wr[c4];
        acc += a.x * b.x + a.y * b.y + a.z * b.z + a.w * b.w;
    }
    if (e < DIN) xm[e * LL + l] = acc;
    else         z[l * DIN + (e - DIN)] = acc;
}

// ---- Kernel 2: depthwise 3x3x3 conv + bias + SiLU, emitting 4 PRE-PERMUTED
// copies xcp[p][d][l']. Block per channel d; whole 16^3 volume in padded LDS.
__global__ __launch_bounds__(1024) void k_conv(const float* __restrict__ xm,
                                               const float* __restrict__ cw,
                                               const float* __restrict__ cb,
                                               float* __restrict__ xcp) {
    int d = blockIdx.x;
    int tid = threadIdx.x;
    __shared__ float xin[4366];
    __shared__ float xout[4366];
    {
        float4 v = ((const float4*)(xm + (size_t)d * LL))[tid];
        int o = OL(tid * 4);                           // 4j stays in-group
        xin[o] = v.x; xin[o + 1] = v.y; xin[o + 2] = v.z; xin[o + 3] = v.w;
    }
    __syncthreads();
    const float* wp = cw + d * 27;
    float bias = cb[d];
#pragma unroll
    for (int j = 0; j < 4; ++j) {
        int s = tid * 4 + j;
        int dd = s & 15, w = (s >> 4) & 15, h = s >> 8;
        float acc = 0.f;
#pragma unroll
        for (int i = -1; i <= 1; ++i) {
            int hh = h + i; if (hh < 0 || hh > 15) continue;
#pragma unroll
            for (int jj = -1; jj <= 1; ++jj) {
                int ww2 = w + jj; if (ww2 < 0 || ww2 > 15) continue;
#pragma unroll
                for (int q = -1; q <= 1; ++q) {
                    int dd2 = dd + q; if (dd2 < 0 || dd2 > 15) continue;
                    acc += wp[(i + 1) * 9 + (jj + 1) * 3 + (q + 1)]
                         * xin[OL(hh * 256 + ww2 * 16 + dd2)];
                }
            }
        }
        acc += bias;
        xout[OL(s)] = acc / (1.f + __expf(-acc));      // SiLU
    }
    __syncthreads();
#pragma unroll
    for (int p = 0; p < 4; ++p) {
        float4 v;
#pragma unroll
        for (int j = 0; j < 4; ++j) {
            int lp = tid * 4 + j;
            (&v.x)[j] = xout[OL(perm_src(lp, p))];
        }
        ((float4*)(xcp + ((size_t)p * DIN + d) * LL))[tid] = v;
    }
}

// ---- Kernel 3: frontend + local scan; emits ylocal/cumdelta, C, (pa,hf). ---
// Telescoped-seed identity: y[i] = ylocal[i] + sum_n C_n[i]*exp(A_n*cum[i])*h0_n
// where ylocal = sum_n C_n*S_n + D*u (S = zero-seeded local scan) and cum is
// the within-chunk prefix of delta. So pass 2 needs NO recurrence and NO
// frontend — just this kernel's outputs.
__global__ __launch_bounds__(768) void k_scanA(const float* __restrict__ xcp,
                                               const float* __restrict__ xpw,
                                               const float* __restrict__ dtw,
                                               const float* __restrict__ dtb,
                                               const float* __restrict__ A_logs,
                                               const float* __restrict__ Ds,
                                               float* __restrict__ yl_g,
                                               float* __restrict__ C_g,
                                               float* __restrict__ phf_g) {
    int k = blockIdx.x >> 6;
    int c = blockIdx.x & (NCH - 1);
    int l0 = c * CHL;
    int tid = threadIdx.x;
    __shared__ float  xt[48 * 68];                     // u tile
    __shared__ float  xd[35 * 65];                     // x_dbl [cc][64]
    __shared__ float2 ud[48 * 68];                     // (u, delta)
    __shared__ float2 yl[48 * 64];                     // (ylocal, cumdelta)
    int kperm = k & 3, krev = k & 4;
    // coalesced stage from the pre-permuted copy (1 float4/thread)
    {
        int d = tid >> 4, q = tid & 15;
        const float* row = xcp + ((size_t)kperm * DIN + d) * LL;
        if (!krev) {
            float4 v = ((const float4*)(row + l0))[q];
            xt[d * 68 + q * 4 + 0] = v.x; xt[d * 68 + q * 4 + 1] = v.y;
            xt[d * 68 + q * 4 + 2] = v.z; xt[d * 68 + q * 4 + 3] = v.w;
        } else {
            float4 v = ((const float4*)(row + (LL - CHL - l0)))[15 - q];
            xt[d * 68 + q * 4 + 3] = v.x; xt[d * 68 + q * 4 + 2] = v.y;
            xt[d * 68 + q * 4 + 1] = v.z; xt[d * 68 + q * 4 + 0] = v.w;
        }
    }
    __syncthreads();
    // GEMM: x_dbl[cc][l] = sum_d u[d][l] * xpw[k][cc][d]
    if (tid < 560) {
        int cc = tid % 35, l4 = tid / 35;
        const float* wr = xpw + (k * 35 + cc) * DIN;   // L1-broadcast
        float4 acc = {0.f, 0.f, 0.f, 0.f};
#pragma unroll
        for (int d2 = 0; d2 < 48; ++d2) {
            float4 v = ((const float4*)(xt + d2 * 68))[l4];
            float w = wr[d2];
            acc.x += v.x * w; acc.y += v.y * w; acc.z += v.z * w; acc.w += v.w * w;
        }
        float* o = xd + cc * 65 + l4 * 4;
        o[0] = acc.x; o[1] = acc.y; o[2] = acc.z; o[3] = acc.w;
    }
    __syncthreads();
    // delta = softplus(dts @ dtw + bias); pack (u,delta) to LDS
#pragma unroll
    for (int r = 0; r < 4; ++r) {
        int item = r * 768 + tid;
        int d2 = item >> 6, l = item & 63;
        int gd = k * DIN + d2;
        float v = xd[l] * dtw[gd * 3] + xd[65 + l] * dtw[gd * 3 + 1]
                + xd[130 + l] * dtw[gd * 3 + 2] + dtb[gd];
        float sp = (v > 20.f) ? v : log1pf(__expf(v));
        ud[d2 * 68 + l] = make_float2(xt[d2 * 68 + l], sp);
    }
    __syncthreads();
    // C tile out (coalesced: 64 consecutive floats per lane-quad)
    if (tid < 256) {
        int l = tid >> 2, q = tid & 3;
        float4 v;
#pragma unroll
        for (int j = 0; j < 4; ++j) (&v.x)[j] = xd[(19 + q * 4 + j) * 65 + l];
        ((float4*)(C_g + ((size_t)(k * LL + l0 + l)) * 16))[q] = v;
    }
    // local zero-seeded scan: S, cumdelta, ylocal(+D*u)
    int d = tid >> 4, n = tid & 15;
    int gid = k * DIN + d;
    float A = -__expf(A_logs[gid * NN + n]);
    float Dv = Ds[gid];
    float S = 0.f, cum = 0.f;
#pragma unroll 8
    for (int i = 0; i < CHL; ++i) {
        float2 uv = ud[d * 68 + i];
        float Bv = xd[(3 + n) * 65 + i];
        cum += uv.y;
        float dA = __expf(uv.y * A);
        S = S * dA + uv.y * uv.x * Bv;
        float t = row16_sum(S * xd[(19 + n) * 65 + i]);
        if (n == 0) yl[d * 64 + i] = make_float2(t + Dv * uv.x, cum);
    }
    // chunk summary: pa = exp(A*cum) (telescoped product), hf = S
    ((float2*)phf_g)[(size_t)gid * (NCH * 16) + c * 16 + n] =
        make_float2(__expf(A * cum), S);
    __syncthreads();
    // bulk write yl tile (coalesced float4, 2/thread)
#pragma unroll
    for (int r = 0; r < 2; ++r) {
        int item = r * 768 + tid;                      // 1536 float4
        int d2 = item >> 5, q = item & 31;
        ((float4*)yl_g)[((size_t)(k * DIN + d2) * LL + l0) / 2 + q] =
            ((const float4*)yl)[d2 * 32 + q];
    }
}

// ---- Kernel 4: seed chain + PARALLEL correction + de-permuted y2 store. ----
// No recurrence: every i is independent -> full ILP / unrolling.
__global__ __launch_bounds__(768) void k_scanB(const float* __restrict__ yl_g,
                                               const float* __restrict__ C_g,
                                               const float* __restrict__ A_logs,
                                               const float* __restrict__ phf_g,
                                               float* __restrict__ y2) {
    int k = blockIdx.x >> 6;
    int c = blockIdx.x & (NCH - 1);
    int l0 = c * CHL;
    int tid = threadIdx.x;
    int d = tid >> 4, n = tid & 15;
    int gid = k * DIN + d;
    __shared__ float2 ylc[48 * 64];                    // (ylocal, cumdelta)
    __shared__ float  sc[64 * 16];                     // C [i][n]
    __shared__ float  y_t[48 * 68];
    // stage (ylocal,cum) tile: 1536 float4, 2/thread, coalesced
#pragma unroll
    for (int r = 0; r < 2; ++r) {
        int item = r * 768 + tid;
        int d2 = item >> 5, q = item & 31;
        ((float4*)ylc)[d2 * 32 + q] =
            ((const float4*)yl_g)[((size_t)(k * DIN + d2) * LL + l0) / 2 + q];
    }
    // stage C tile: 256 float4 (1024 contiguous floats)
    if (tid < 256)
        ((float4*)sc)[tid] = ((const float4*)(C_g + (size_t)(k * LL + l0) * 16))[tid];
    float A = -__expf(A_logs[gid * NN + n]);
    // seed = exclusive combine of chunks [0,c); 8 independent loads/group
    float h0 = 0.f;
    {
        const float2* pp = ((const float2*)phf_g) + (size_t)gid * (NCH * 16) + n;
        int cc = 0;
        for (; cc + 8 <= c; cc += 8) {
            float2 v0 = pp[(cc + 0) * 16]; float2 v1 = pp[(cc + 1) * 16];
            float2 v2 = pp[(cc + 2) * 16]; float2 v3 = pp[(cc + 3) * 16];
            float2 v4 = pp[(cc + 4) * 16]; float2 v5 = pp[(cc + 5) * 16];
            float2 v6 = pp[(cc + 6) * 16]; float2 v7 = pp[(cc + 7) * 16];
            h0 = h0 * v0.x + v0.y; h0 = h0 * v1.x + v1.y;
            h0 = h0 * v2.x + v2.y; h0 = h0 * v3.x + v3.y;
            h0 = h0 * v4.x + v4.y; h0 = h0 * v5.x + v5.y;
            h0 = h0 * v6.x + v6.y; h0 = h0 * v7.x + v7.y;
        }
        for (; cc < c; ++cc) { float2 v = pp[cc * 16]; h0 = h0 * v.x + v.y; }
    }
    __syncthreads();                                   // staging visible
    // parallel correction: y[i] = ylocal[i] + sum_n C_n[i]*exp(A*cum[i])*h0
#pragma unroll 8
    for (int i = 0; i < CHL; ++i) {
        float2 yc = ylc[d * 64 + i];
        float t = sc[i * 16 + n] * __expf(A * yc.y) * h0;
        float s = row16_sum(t);
        if (n == 0) y_t[d * 68 + i] = yc.x + s;
    }
    __syncthreads();
    // de-permuted store: y2[s][k*48..+47], 192B contiguous per (l)
    {
        int g = tid >> 6, l = tid & 63;                // g: 0..11
        int lg = l0 + l;
        int ll = (k & 4) ? (LL - 1 - lg) : lg;
        int sp = perm_src(ll, k & 3);
        float4 v;
#pragma unroll
        for (int j = 0; j < 4; ++j) (&v.x)[j] = y_t[(g * 4 + j) * 68 + l];
        ((float4*)(y2 + (size_t)sp * KD + k * DIN))[g] = v;
    }
}

// ---- Kernel 5: sum dirs + LayerNorm + gate + out_proj. Wave per s. ---------
__global__ __launch_bounds__(256) void k_final2(const float* __restrict__ y2,
                                                const float* __restrict__ z,
                                                const float* __restrict__ nw,
                                                const float* __restrict__ nb,
                                                const float* __restrict__ opw,
                                                float* __restrict__ out) {
    int wv = threadIdx.x >> 6, lane = threadIdx.x & 63;
    int s = blockIdx.x * 4 + wv;
    __shared__ float g[4][DIN];
    float val = 0.f;
    if (lane < DIN) {
        const float* yp = y2 + (size_t)s * KD + lane;
#pragma unroll
        for (int k = 0; k < KK; ++k) val += yp[k * DIN];
    }
    float m = val;
#pragma unroll
    for (int o = 32; o >= 1; o >>= 1) m += __shfl_xor(m, o, 64);
    m *= (1.f / 48.f);
    float dv = (lane < DIN) ? (val - m) : 0.f;
    float v2 = dv * dv;
#pragma unroll
    for (int o = 32; o >= 1; o >>= 1) v2 += __shfl_xor(v2, o, 64);
    v2 *= (1.f / 48.f);
    float inv = rsqrtf(v2 + 1e-5f);
    if (lane < DIN) {
        float yn = dv * inv * nw[lane] + nb[lane];
        float zz = z[s * DIN + lane];
        g[wv][lane] = yn * (zz / (1.f + __expf(-zz)));
    }
    __syncthreads();
    if (lane < DIN) {
        const float* wr = opw + lane * DIN;            // out_proj_w[c, e]
        float acc = 0.f;
#pragma unroll
        for (int e = 0; e < DIN; ++e) acc += g[wv][e] * wr[e];
        out[s * CC + lane] = acc;
    }
}

extern "C" void kernel_launch(void* const* d_in, const int* in_sizes, int n_in,
                              void* d_out, int out_size, void* d_ws, size_t ws_size,
                              hipStream_t stream) {
    const float* x      = (const float*)d_in[0];
    const float* ipw    = (const float*)d_in[1];
    const float* cw     = (const float*)d_in[2];
    const float* cb     = (const float*)d_in[3];
    const float* xpw    = (const float*)d_in[4];
    const float* dtw    = (const float*)d_in[5];
    const float* dtb    = (const float*)d_in[6];
    const float* A_logs = (const float*)d_in[7];
    const float* Ds     = (const float*)d_in[8];
    const float* nw     = (const float*)d_in[9];
    const float* nb     = (const float*)d_in[10];
    const float* opw    = (const float*)d_in[11];
    float* out = (float*)d_out;

    float* ws    = (float*)d_ws;
    float* xm    = ws;                                 // DIN*LL
    float* z     = xm + DIN * LL;                      // LL*DIN
    float* xcp   = z + LL * DIN;                       // 4*DIN*LL (perm copies)
    float* y2    = xcp + (size_t)4 * DIN * LL;         // LL*KD (s-major)
    float* yl_g  = y2 + (size_t)LL * KD;               // 2*KD*LL (float2)
    float* C_g   = yl_g + (size_t)2 * KD * LL;         // KK*LL*16
    float* phf_g = C_g + (size_t)KK * LL * 16;         // 2*KD*NCH*16 (float2)

    k_inproj<<<(LL * 96 + 255) / 256, 256, 0, stream>>>(x, ipw, xm, z);
    k_conv<<<DIN, 1024, 0, stream>>>(xm, cw, cb, xcp);
    k_scanA<<<KK * NCH, 768, 0, stream>>>(xcp, xpw, dtw, dtb, A_logs, Ds,
                                          yl_g, C_g, phf_g);
    k_scanB<<<KK * NCH, 768, 0, stream>>>(yl_g, C_g, A_logs, phf_g, y2);
    k_final2<<<LL / 4, 256, 0, stream>>>(y2, z, nw, nb, opw, out);
}

// Round 9
// 147.201 us; speedup vs baseline: 1.2041x; 1.0130x over previous
//
#include <hip/hip_runtime.h>
#include <math.h>

// Problem constants (B=1)
#define HH 16
#define WW 16
#define DD 16
#define LL 4096          // H*W*Dd
#define CC 48            // d_model
#define DIN 48           // d_inner
#define NN 16            // d_state
#define RR 3             // dt_rank
#define KK 8             // scan directions
#define KD 384           // K*DIN
#define NCH 64           // chunks along L
#define CHL 64           // chunk length

// Multi-stride LDS pad for a 16x16x16 volume: conflict-free at strides
// 1 (dd), 16 (w: 17 mod 32), 256 (h: 273 mod 32 = 17). Max idx 4365.
#define OL(s) ((s) + ((s) >> 4) + ((s) >> 8))

// DPP-based 16-lane (within-row) sum: xor1, xor2 via quad_perm; then
// row_ror:4 + row_ror:8 complete the 16-lane reduction. Pure VALU, no LDS.
__device__ __forceinline__ float dpp_add(float x, const int ctrl_tag) {
    int xi = __float_as_int(x);
    int yi;
    switch (ctrl_tag) {
        case 0: yi = __builtin_amdgcn_update_dpp(0, xi, 0xB1, 0xF, 0xF, true); break; // quad_perm [1,0,3,2]
        case 1: yi = __builtin_amdgcn_update_dpp(0, xi, 0x4E, 0xF, 0xF, true); break; // quad_perm [2,3,0,1]
        case 2: yi = __builtin_amdgcn_update_dpp(0, xi, 0x124, 0xF, 0xF, true); break; // row_ror:4
        default: yi = __builtin_amdgcn_update_dpp(0, xi, 0x128, 0xF, 0xF, true); break; // row_ror:8
    }
    return x + __int_as_float(yi);
}
__device__ __forceinline__ float row16_sum(float p) {
    p = dpp_add(p, 0);
    p = dpp_add(p, 1);
    p = dpp_add(p, 2);
    p = dpp_add(p, 3);
    return p;
}

// scan-index -> natural-site map
__device__ __forceinline__ int perm_src(int ll, int kperm) {
    int a = ll >> 8, b2 = (ll >> 4) & 15, c2 = ll & 15;
    switch (kperm) {
        case 0:  return ll;
        case 1:  return b2 * 256 + a * 16 + c2;
        case 2:  return c2 * 256 + b2 * 16 + a;
        default: return a * 256 + c2 * 16 + b2;
    }
}

// ---- Kernel 1: fused in_proj + depthwise conv + SiLU + 4 permuted copies,
// plus the z (gate) half of in_proj. 60 blocks x 1024 threads:
//   blocks 0..47  : channel d — in_proj row d computed IN-REGISTER from x
//                   (xm buffer deleted), conv stencil in padded LDS, then
//                   4 pre-permuted xcp copies (proven v2 code).
//   blocks 48..59 : z columns e0=4b..4b+3, float4 stores (l-major layout).
__global__ __launch_bounds__(1024) void k_front(const float* __restrict__ x,
                                                const float* __restrict__ ipw,
                                                const float* __restrict__ cw,
                                                const float* __restrict__ cb,
                                                float* __restrict__ xcp,
                                                float* __restrict__ z) {
    int tid = threadIdx.x;
    if (blockIdx.x < DIN) {
        int d = blockIdx.x;
        __shared__ float xin[4366];
        __shared__ float xout[4366];
        // in_proj row d: xin[OL(l)] = dot(x[l, 0:48], ipw[d, 0:48])
        {
            const float4* wr = (const float4*)(ipw + d * CC);
            float4 w[12];
#pragma unroll
            for (int c4 = 0; c4 < 12; ++c4) w[c4] = wr[c4];
#pragma unroll
            for (int r = 0; r < 4; ++r) {
                int l = r * 1024 + tid;
                const float4* xr = (const float4*)(x + (size_t)l * CC);
                float acc = 0.f;
#pragma unroll
                for (int c4 = 0; c4 < 12; ++c4) {
                    float4 a = xr[c4];
                    acc += a.x * w[c4].x + a.y * w[c4].y
                         + a.z * w[c4].z + a.w * w[c4].w;
                }
                xin[OL(l)] = acc;
            }
        }
        __syncthreads();
        const float* wp = cw + d * 27;
        float bias = cb[d];
#pragma unroll
        for (int j = 0; j < 4; ++j) {
            int s = tid * 4 + j;
            int dd = s & 15, w = (s >> 4) & 15, h = s >> 8;
            float acc = 0.f;
#pragma unroll
            for (int i = -1; i <= 1; ++i) {
                int hh = h + i; if (hh < 0 || hh > 15) continue;
#pragma unroll
                for (int jj = -1; jj <= 1; ++jj) {
                    int ww2 = w + jj; if (ww2 < 0 || ww2 > 15) continue;
#pragma unroll
                    for (int q = -1; q <= 1; ++q) {
                        int dd2 = dd + q; if (dd2 < 0 || dd2 > 15) continue;
                        acc += wp[(i + 1) * 9 + (jj + 1) * 3 + (q + 1)]
                             * xin[OL(hh * 256 + ww2 * 16 + dd2)];
                    }
                }
            }
            acc += bias;
            xout[OL(s)] = acc / (1.f + __expf(-acc));  // SiLU
        }
        __syncthreads();
#pragma unroll
        for (int p = 0; p < 4; ++p) {
            float4 v;
#pragma unroll
            for (int j = 0; j < 4; ++j) {
                int lp = tid * 4 + j;
                (&v.x)[j] = xout[OL(perm_src(lp, p))];
            }
            ((float4*)(xcp + ((size_t)p * DIN + d) * LL))[tid] = v;
        }
    } else {
        int e0 = (blockIdx.x - DIN) * 4;               // z columns e0..e0+3
#pragma unroll
        for (int r = 0; r < 4; ++r) {
            int l = r * 1024 + tid;
            const float4* xr = (const float4*)(x + (size_t)l * CC);
            float4 xv[12];
#pragma unroll
            for (int c4 = 0; c4 < 12; ++c4) xv[c4] = xr[c4];
            float4 out;
#pragma unroll
            for (int j = 0; j < 4; ++j) {
                const float4* wj = (const float4*)(ipw + (size_t)(DIN + e0 + j) * CC);
                float acc = 0.f;
#pragma unroll
                for (int c4 = 0; c4 < 12; ++c4) {
                    float4 b = wj[c4];                 // L1-broadcast
                    acc += xv[c4].x * b.x + xv[c4].y * b.y
                         + xv[c4].z * b.z + xv[c4].w * b.w;
                }
                (&out.x)[j] = acc;
            }
            *((float4*)(z + (size_t)l * DIN + e0)) = out;
        }
    }
}

// ---- Kernel 2: coalesced frontend + scan PHASE 1; emits BC, ud_g, phf. -----
// R4's xscan1 outputs with the R5/R6-proven coalesced xcp staging (the last
// permuted element-gather is gone).
__global__ __launch_bounds__(768) void k_scan1(const float* __restrict__ xcp,
                                               const float* __restrict__ xpw,
                                               const float* __restrict__ dtw,
                                               const float* __restrict__ dtb,
                                               const float* __restrict__ A_logs,
                                               float* __restrict__ BC,
                                               float* __restrict__ ud_g,
                                               float* __restrict__ phf_g) {
    int k = blockIdx.x >> 6;
    int c = blockIdx.x & (NCH - 1);
    int l0 = c * CHL;
    int tid = threadIdx.x;
    __shared__ float  xt[48 * 68];                     // u tile [d][64]
    __shared__ float  xd[35 * 65];                     // x_dbl [cc][64]
    __shared__ float2 ud[48 * 68];                     // (u, delta)
    int kperm = k & 3, krev = k & 4;
    // coalesced stage from the pre-permuted copy (1 float4/thread)
    {
        int d = tid >> 4, q = tid & 15;
        const float* row = xcp + ((size_t)kperm * DIN + d) * LL;
        if (!krev) {
            float4 v = ((const float4*)(row + l0))[q];
            xt[d * 68 + q * 4 + 0] = v.x; xt[d * 68 + q * 4 + 1] = v.y;
            xt[d * 68 + q * 4 + 2] = v.z; xt[d * 68 + q * 4 + 3] = v.w;
        } else {
            float4 v = ((const float4*)(row + (LL - CHL - l0)))[15 - q];
            xt[d * 68 + q * 4 + 3] = v.x; xt[d * 68 + q * 4 + 2] = v.y;
            xt[d * 68 + q * 4 + 1] = v.z; xt[d * 68 + q * 4 + 0] = v.w;
        }
    }
    __syncthreads();
    // GEMM: x_dbl[cc][l] = sum_d u[d][l] * xpw[k][cc][d]
    if (tid < 560) {
        int cc = tid % 35, l4 = tid / 35;
        const float* wr = xpw + (k * 35 + cc) * DIN;   // L1-broadcast
        float4 acc = {0.f, 0.f, 0.f, 0.f};
#pragma unroll
        for (int d2 = 0; d2 < 48; ++d2) {
            float4 v = ((const float4*)(xt + d2 * 68))[l4];
            float w = wr[d2];
            acc.x += v.x * w; acc.y += v.y * w; acc.z += v.z * w; acc.w += v.w * w;
        }
        float* o = xd + cc * 65 + l4 * 4;
        o[0] = acc.x; o[1] = acc.y; o[2] = acc.z; o[3] = acc.w;
    }
    __syncthreads();
    // BC write (float4 over 32 cols)
    if (tid < 512) {
        int l = tid >> 3, q = tid & 7;
        float4 v;
#pragma unroll
        for (int j = 0; j < 4; ++j) (&v.x)[j] = xd[(3 + q * 4 + j) * 65 + l];
        ((float4*)(BC + ((size_t)(k * LL + l0 + l)) * 32))[q] = v;
    }
    // delta = softplus(dts @ dtw + bias); pack (u,delta) to LDS + global
#pragma unroll
    for (int r = 0; r < 4; ++r) {
        int item = r * 768 + tid;
        int d2 = item >> 6, l = item & 63;
        int gd = k * DIN + d2;
        float v = xd[l] * dtw[gd * 3] + xd[65 + l] * dtw[gd * 3 + 1]
                + xd[130 + l] * dtw[gd * 3 + 2] + dtb[gd];
        float sp = (v > 20.f) ? v : log1pf(__expf(v));
        float u = xt[d2 * 68 + l];
        float2 p = make_float2(u, sp);
        ud[d2 * 68 + l] = p;
        ((float2*)ud_g)[(size_t)gd * LL + l0 + l] = p;
    }
    __syncthreads();
    // scan phase 1: local chunk scan (h starts at 0) -> packed (pa, hf)
    int d = tid >> 4, n = tid & 15;
    int gid = k * DIN + d;
    float A = -__expf(A_logs[gid * NN + n]);
    float h = 0.f, pa = 1.f;
#pragma unroll 8
    for (int i = 0; i < CHL; ++i) {
        float2 uv = ud[d * 68 + i];
        float Bv = xd[(3 + n) * 65 + i];
        float dA = __expf(uv.y * A);
        h = h * dA + uv.y * uv.x * Bv;
        pa *= dA;
    }
    ((float2*)phf_g)[(size_t)gid * (NCH * 16) + c * 16 + n] = make_float2(pa, h);
}

// ---- Kernel 3: scan PHASE 2+3 fused, LDS-staged (R4 champion, unchanged). --
__global__ __launch_bounds__(768, 6) void k_scan3(const float* __restrict__ ud_g,
                                                  const float* __restrict__ BC,
                                                  const float* __restrict__ A_logs,
                                                  const float* __restrict__ Ds,
                                                  const float* __restrict__ phf_g,
                                                  float* __restrict__ y2) {
    int k = blockIdx.x >> 6;
    int c = blockIdx.x & (NCH - 1);
    int l0 = c * CHL;
    int tid = threadIdx.x;
    int d = tid >> 4, n = tid & 15;
    int gid = k * DIN + d;
    __shared__ float2 s_ud[48 * 64];                   // (u,delta) [d][i]
    __shared__ float  s_bc[64 * 32];                   // B,C [i][32]
    __shared__ float  y_t[48 * 68];

    // --- bulk staging: 1536 float4 of ud + 512 float4 of BC, coalesced
    const float4* ud4 = (const float4*)ud_g;
    const float4* bc4 = (const float4*)BC;
    int r0 = tid >> 5, q0 = tid & 31;                  // ud: row 0..47, col 0..31
    float4 ua = ud4[(size_t)(k * DIN + r0)      * (LL / 2) + (l0 / 2) + q0];
    float4 ub = ud4[(size_t)(k * DIN + 24 + r0) * (LL / 2) + (l0 / 2) + q0];
    float4 bv;
    if (tid < 512) bv = bc4[((size_t)(k * LL + l0 + (tid >> 3))) * 8 + (tid & 7)];
    ((float4*)s_ud)[tid] = ua;
    ((float4*)s_ud)[768 + tid] = ub;
    if (tid < 512) ((float4*)s_bc)[tid] = bv;

    float A = -__expf(A_logs[gid * NN + n]);
    float Dv = Ds[gid];

    // --- seed: exclusive combine of chunks [0, c); 8 independent loads/group
    float h = 0.f;
    {
        const float2* pp = ((const float2*)phf_g) + (size_t)gid * (NCH * 16) + n;
        int cc = 0;
        for (; cc + 8 <= c; cc += 8) {
            float2 v0 = pp[(cc + 0) * 16]; float2 v1 = pp[(cc + 1) * 16];
            float2 v2 = pp[(cc + 2) * 16]; float2 v3 = pp[(cc + 3) * 16];
            float2 v4 = pp[(cc + 4) * 16]; float2 v5 = pp[(cc + 5) * 16];
            float2 v6 = pp[(cc + 6) * 16]; float2 v7 = pp[(cc + 7) * 16];
            h = h * v0.x + v0.y; h = h * v1.x + v1.y;
            h = h * v2.x + v2.y; h = h * v3.x + v3.y;
            h = h * v4.x + v4.y; h = h * v5.x + v5.y;
            h = h * v6.x + v6.y; h = h * v7.x + v7.y;
        }
        for (; cc < c; ++cc) { float2 v = pp[cc * 16]; h = h * v.x + v.y; }
    }
    __syncthreads();                                   // staging visible

    // --- seeded re-scan, fully LDS-fed
    const float2* ur = s_ud + d * 64;
#pragma unroll 8
    for (int i = 0; i < CHL; ++i) {
        float2 uv = ur[i];
        float Bv = s_bc[i * 32 + n];
        float Cv = s_bc[i * 32 + 16 + n];
        float dA = __expf(uv.y * A);
        h = h * dA + uv.y * uv.x * Bv;
        float p = row16_sum(h * Cv);                   // pure-VALU 16-lane sum
        if (n == 0) y_t[d * 68 + i] = p + Dv * uv.x;
    }
    __syncthreads();
    // de-permuted store: y2[s][k*48..+47], 192B contiguous per (l)
    {
        int g = tid >> 6, l = tid & 63;                // g: 0..11
        int lg = l0 + l;
        int ll = (k & 4) ? (LL - 1 - lg) : lg;
        int sp = perm_src(ll, k & 3);
        float4 v;
#pragma unroll
        for (int j = 0; j < 4; ++j) (&v.x)[j] = y_t[(g * 4 + j) * 68 + l];
        ((float4*)(y2 + (size_t)sp * KD + k * DIN))[g] = v;
    }
}

// ---- Kernel 4: sum dirs + LayerNorm + gate + out_proj. Wave per s. ---------
__global__ __launch_bounds__(256) void k_final2(const float* __restrict__ y2,
                                                const float* __restrict__ z,
                                                const float* __restrict__ nw,
                                                const float* __restrict__ nb,
                                                const float* __restrict__ opw,
                                                float* __restrict__ out) {
    int wv = threadIdx.x >> 6, lane = threadIdx.x & 63;
    int s = blockIdx.x * 4 + wv;
    __shared__ float g[4][DIN];
    float val = 0.f;
    if (lane < DIN) {
        const float* yp = y2 + (size_t)s * KD + lane;
#pragma unroll
        for (int k = 0; k < KK; ++k) val += yp[k * DIN];
    }
    float m = val;
#pragma unroll
    for (int o = 32; o >= 1; o >>= 1) m += __shfl_xor(m, o, 64);
    m *= (1.f / 48.f);
    float dv = (lane < DIN) ? (val - m) : 0.f;
    float v2 = dv * dv;
#pragma unroll
    for (int o = 32; o >= 1; o >>= 1) v2 += __shfl_xor(v2, o, 64);
    v2 *= (1.f / 48.f);
    float inv = rsqrtf(v2 + 1e-5f);
    if (lane < DIN) {
        float yn = dv * inv * nw[lane] + nb[lane];
        float zz = z[s * DIN + lane];
        g[wv][lane] = yn * (zz / (1.f + __expf(-zz)));
    }
    __syncthreads();
    if (lane < DIN) {
        const float* wr = opw + lane * DIN;            // out_proj_w[c, e]
        float acc = 0.f;
#pragma unroll
        for (int e = 0; e < DIN; ++e) acc += g[wv][e] * wr[e];
        out[s * CC + lane] = acc;
    }
}

extern "C" void kernel_launch(void* const* d_in, const int* in_sizes, int n_in,
                              void* d_out, int out_size, void* d_ws, size_t ws_size,
                              hipStream_t stream) {
    const float* x      = (const float*)d_in[0];
    const float* ipw    = (const float*)d_in[1];
    const float* cw     = (const float*)d_in[2];
    const float* cb     = (const float*)d_in[3];
    const float* xpw    = (const float*)d_in[4];
    const float* dtw    = (const float*)d_in[5];
    const float* dtb    = (const float*)d_in[6];
    const float* A_logs = (const float*)d_in[7];
    const float* Ds     = (const float*)d_in[8];
    const float* nw     = (const float*)d_in[9];
    const float* nb     = (const float*)d_in[10];
    const float* opw    = (const float*)d_in[11];
    float* out = (float*)d_out;

    float* ws    = (float*)d_ws;
    float* z     = ws;                                 // LL*DIN
    float* xcp   = z + (size_t)LL * DIN;               // 4*DIN*LL (perm copies)
    float* ud_g  = xcp + (size_t)4 * DIN * LL;         // 2*KD*LL (float2)
    float* BC    = ud_g + (size_t)2 * KD * LL;         // KK*LL*32
    float* y2    = BC + (size_t)KK * LL * 32;          // LL*KD (s-major)
    float* phf_g = y2 + (size_t)LL * KD;               // 2*KD*NCH*16 (float2)

    k_front<<<DIN + 12, 1024, 0, stream>>>(x, ipw, cw, cb, xcp, z);
    k_scan1<<<KK * NCH, 768, 0, stream>>>(xcp, xpw, dtw, dtb, A_logs,
                                          BC, ud_g, phf_g);
    k_scan3<<<KK * NCH, 768, 0, stream>>>(ud_g, BC, A_logs, Ds, phf_g, y2);
    k_final2<<<LL / 4, 256, 0, stream>>>(y2, z, nw, nb, opw, out);
}

// Round 10
// 143.733 us; speedup vs baseline: 1.2331x; 1.0241x over previous
//
#include <hip/hip_runtime.h>
#include <hip/hip_bf16.h>
#include <math.h>

// Problem constants (B=1)
#define HH 16
#define WW 16
#define DD 16
#define LL 4096          // H*W*Dd
#define CC 48            // d_model
#define DIN 48           // d_inner
#define NN 16            // d_state
#define RR 3             // dt_rank
#define KK 8             // scan directions
#define KD 384           // K*DIN
#define NCH 64           // chunks along L
#define CHL 64           // chunk length

// DPP-based 16-lane (within-row) sum: xor1, xor2 via quad_perm; then
// row_ror:4 + row_ror:8 complete the 16-lane reduction. Pure VALU, no LDS.
__device__ __forceinline__ float dpp_add(float x, const int ctrl_tag) {
    int xi = __float_as_int(x);
    int yi;
    switch (ctrl_tag) {
        case 0: yi = __builtin_amdgcn_update_dpp(0, xi, 0xB1, 0xF, 0xF, true); break; // quad_perm [1,0,3,2]
        case 1: yi = __builtin_amdgcn_update_dpp(0, xi, 0x4E, 0xF, 0xF, true); break; // quad_perm [2,3,0,1]
        case 2: yi = __builtin_amdgcn_update_dpp(0, xi, 0x124, 0xF, 0xF, true); break; // row_ror:4
        default: yi = __builtin_amdgcn_update_dpp(0, xi, 0x128, 0xF, 0xF, true); break; // row_ror:8
    }
    return x + __int_as_float(yi);
}
__device__ __forceinline__ float row16_sum(float p) {
    p = dpp_add(p, 0);
    p = dpp_add(p, 1);
    p = dpp_add(p, 2);
    p = dpp_add(p, 3);
    return p;
}

// ---------------- Kernel 1: in_proj  xz[l,e] = sum_c x[l,c]*W[e,c] ----------
__global__ __launch_bounds__(256) void k_inproj(const float* __restrict__ x,
                                                const float* __restrict__ W,
                                                float* __restrict__ xm,
                                                float* __restrict__ z) {
    int tid = blockIdx.x * 256 + threadIdx.x;          // l*96 + e
    if (tid >= LL * 96) return;
    int e = tid % 96, l = tid / 96;
    const float4* xr = (const float4*)(x + l * CC);
    const float4* wr = (const float4*)(W + e * CC);
    float acc = 0.f;
#pragma unroll
    for (int c4 = 0; c4 < CC / 4; ++c4) {
        float4 a = xr[c4], b = wr[c4];
        acc += a.x * b.x + a.y * b.y + a.z * b.z + a.w * b.w;
    }
    if (e < DIN) xm[e * LL + l] = acc;
    else         z[l * DIN + (e - DIN)] = acc;
}

// ---- Kernel 2: depthwise 3x3x3 conv + bias + SiLU (natural layout only) ----
__global__ __launch_bounds__(256) void k_conv(const float* __restrict__ xm,
                                              const float* __restrict__ cw,
                                              const float* __restrict__ cb,
                                              float* __restrict__ xc) {
    int tid = blockIdx.x * 256 + threadIdx.x;          // d*LL + s
    if (tid >= DIN * LL) return;
    int s = tid & (LL - 1), d = tid >> 12;
    int dd = s & 15, w = (s >> 4) & 15, h = s >> 8;
    const float* wp = cw + d * 27;
    const float* xp = xm + d * LL;
    float acc = 0.f;
#pragma unroll
    for (int i = -1; i <= 1; ++i) {
        int hh = h + i; if (hh < 0 || hh > 15) continue;
#pragma unroll
        for (int j = -1; j <= 1; ++j) {
            int ww2 = w + j; if (ww2 < 0 || ww2 > 15) continue;
#pragma unroll
            for (int q = -1; q <= 1; ++q) {
                int dd2 = dd + q; if (dd2 < 0 || dd2 > 15) continue;
                acc += wp[(i + 1) * 9 + (j + 1) * 3 + (q + 1)]
                     * xp[hh * 256 + ww2 * 16 + dd2];
            }
        }
    }
    acc += cb[d];
    xc[tid] = acc / (1.f + __expf(-acc));              // SiLU
}

// ---- Kernel 3: permuted gather + x_proj + dt_proj + scan PHASE 1. ----------
// Block per (k, chunk), 768 thr = 48 d x 16 n. u gathered from xc via the
// direction permutation (once). Emits BC, packed ud=(u,delta), phf=(pa,hf).
__global__ __launch_bounds__(768) void k_xscan1(const float* __restrict__ xc,
                                                const float* __restrict__ xpw,
                                                const float* __restrict__ dtw,
                                                const float* __restrict__ dtb,
                                                const float* __restrict__ A_logs,
                                                float* __restrict__ BC,
                                                float* __restrict__ ud_g,
                                                float* __restrict__ phf_g) {
    int k = blockIdx.x >> 6;
    int c = blockIdx.x & (NCH - 1);
    int l0 = c * CHL;
    int tid = threadIdx.x;
    __shared__ float xt[48 * 68];                      // u tile [d][64]
    __shared__ float xd[35 * 65];                      // x_dbl [c][64]
    __shared__ float2 ud[48 * 68];                     // (u, delta)
    int kperm = k & 3, krev = k & 4;
    // stage u tile via permuted gather from natural-layout xc
#pragma unroll
    for (int r = 0; r < 4; ++r) {
        int item = r * 768 + tid;                      // 3072 = 48 d * 64 i
        int d = item >> 6, i = item & 63;
        int lg = l0 + i;
        int ll = krev ? (LL - 1 - lg) : lg;
        int a = ll >> 8, b2 = (ll >> 4) & 15, c2 = ll & 15;
        int src;
        switch (kperm) {
            case 0: src = ll;                       break;
            case 1: src = b2 * 256 + a * 16 + c2;   break;
            case 2: src = c2 * 256 + b2 * 16 + a;   break;
            default: src = a * 256 + c2 * 16 + b2;  break;
        }
        xt[d * 68 + i] = xc[d * LL + src];
    }
    __syncthreads();
    // GEMM: x_dbl[c][l] = sum_d u[d][l] * xpw[k][c][d]
    if (tid < 560) {
        int cc = tid % 35, l4 = tid / 35;
        const float* wr = xpw + (k * 35 + cc) * DIN;   // L1-broadcast
        float4 acc = {0.f, 0.f, 0.f, 0.f};
#pragma unroll
        for (int d2 = 0; d2 < 48; ++d2) {
            float4 v = ((const float4*)(xt + d2 * 68))[l4];
            float w = wr[d2];
            acc.x += v.x * w; acc.y += v.y * w; acc.z += v.z * w; acc.w += v.w * w;
        }
        float* o = xd + cc * 65 + l4 * 4;
        o[0] = acc.x; o[1] = acc.y; o[2] = acc.z; o[3] = acc.w;
    }
    __syncthreads();
    // BC write (float4 over 32 cols)
    if (tid < 512) {
        int l = tid >> 3, q = tid & 7;
        float4 v;
#pragma unroll
        for (int j = 0; j < 4; ++j) (&v.x)[j] = xd[(3 + q * 4 + j) * 65 + l];
        ((float4*)(BC + ((size_t)(k * LL + l0 + l)) * 32))[q] = v;
    }
    // delta = softplus(dts @ dtw + bias); pack (u,delta) to LDS + global
#pragma unroll
    for (int r = 0; r < 4; ++r) {
        int item = r * 768 + tid;
        int d2 = item >> 6, l = item & 63;
        int gd = k * DIN + d2;
        float v = xd[l] * dtw[gd * 3] + xd[65 + l] * dtw[gd * 3 + 1]
                + xd[130 + l] * dtw[gd * 3 + 2] + dtb[gd];
        float sp = (v > 20.f) ? v : log1pf(__expf(v));
        float u = xt[d2 * 68 + l];
        float2 p = make_float2(u, sp);
        ud[d2 * 68 + l] = p;
        ((float2*)ud_g)[(size_t)gd * LL + l0 + l] = p;
    }
    __syncthreads();
    // scan phase 1: local chunk scan (h starts at 0) -> packed (pa, hf)
    int d = tid >> 4, n = tid & 15;
    int gid = k * DIN + d;
    float A = -__expf(A_logs[gid * NN + n]);
    float h = 0.f, pa = 1.f;
#pragma unroll 8
    for (int i = 0; i < CHL; ++i) {
        float2 uv = ud[d * 68 + i];
        float Bv = xd[(3 + n) * 65 + i];
        float dA = __expf(uv.y * A);
        h = h * dA + uv.y * uv.x * Bv;
        pa *= dA;
    }
    size_t si = (size_t)gid * (NCH * 16) + c * 16 + n;
    ((float2*)phf_g)[si] = make_float2(pa, h);
}

// ---- Kernel 4: scan PHASE 2+3 fused, LDS-staged. ---------------------------
// Bulk-stage the chunk's (u,delta) 24KB + BC 8KB into LDS with coalesced
// float4 loads (3/thread, full MLP), 8-way-MLP the seed chain, then run the
// recurrence entirely from LDS. 45.8KB LDS/block; launch_bounds(768,6)
// guarantees VGPR<=84 so 2 blocks/CU (24 waves) stay co-resident.
__global__ __launch_bounds__(768, 6) void k_scan3(const float* __restrict__ ud_g,
                                                  const float* __restrict__ BC,
                                                  const float* __restrict__ A_logs,
                                                  const float* __restrict__ Ds,
                                                  const float* __restrict__ phf_g,
                                                  float* __restrict__ y2) {
    int k = blockIdx.x >> 6;
    int c = blockIdx.x & (NCH - 1);
    int l0 = c * CHL;
    int tid = threadIdx.x;
    int d = tid >> 4, n = tid & 15;
    int gid = k * DIN + d;
    __shared__ float2 s_ud[48 * 64];                   // (u,delta) [d][i]
    __shared__ float  s_bc[64 * 32];                   // B,C [i][32]
    __shared__ float  y_t[48 * 68];

    // --- bulk staging: 1536 float4 of ud + 512 float4 of BC, coalesced
    const float4* ud4 = (const float4*)ud_g;
    const float4* bc4 = (const float4*)BC;
    int r0 = tid >> 5, q0 = tid & 31;                  // ud: row 0..47, col 0..31
    float4 ua = ud4[(size_t)(k * DIN + r0)      * (LL / 2) + (l0 / 2) + q0];
    float4 ub = ud4[(size_t)(k * DIN + 24 + r0) * (LL / 2) + (l0 / 2) + q0];
    float4 bv;
    if (tid < 512) bv = bc4[((size_t)(k * LL + l0 + (tid >> 3))) * 8 + (tid & 7)];
    ((float4*)s_ud)[tid] = ua;
    ((float4*)s_ud)[768 + tid] = ub;
    if (tid < 512) ((float4*)s_bc)[tid] = bv;

    float A = -__expf(A_logs[gid * NN + n]);
    float Dv = Ds[gid];

    // --- seed: exclusive combine of chunks [0, c); 8 independent loads/group
    float h = 0.f;
    {
        const float2* pp = ((const float2*)phf_g) + (size_t)gid * (NCH * 16) + n;
        int cc = 0;
        for (; cc + 8 <= c; cc += 8) {
            float2 v0 = pp[(cc + 0) * 16]; float2 v1 = pp[(cc + 1) * 16];
            float2 v2 = pp[(cc + 2) * 16]; float2 v3 = pp[(cc + 3) * 16];
            float2 v4 = pp[(cc + 4) * 16]; float2 v5 = pp[(cc + 5) * 16];
            float2 v6 = pp[(cc + 6) * 16]; float2 v7 = pp[(cc + 7) * 16];
            h = h * v0.x + v0.y; h = h * v1.x + v1.y;
            h = h * v2.x + v2.y; h = h * v3.x + v3.y;
            h = h * v4.x + v4.y; h = h * v5.x + v5.y;
            h = h * v6.x + v6.y; h = h * v7.x + v7.y;
        }
        for (; cc < c; ++cc) { float2 v = pp[cc * 16]; h = h * v.x + v.y; }
    }
    __syncthreads();                                   // staging visible

    // --- seeded re-scan, fully LDS-fed
    const float2* ur = s_ud + d * 64;
#pragma unroll 8
    for (int i = 0; i < CHL; ++i) {
        float2 uv = ur[i];
        float Bv = s_bc[i * 32 + n];
        float Cv = s_bc[i * 32 + 16 + n];
        float dA = __expf(uv.y * A);
        h = h * dA + uv.y * uv.x * Bv;
        float p = row16_sum(h * Cv);                   // pure-VALU 16-lane sum
        if (n == 0) y_t[d * 68 + i] = p + Dv * uv.x;
    }
    __syncthreads();
    // de-permuted store: y2[s][k*48..+47], 192B contiguous per (l)
    {
        int g = tid >> 6, l = tid & 63;                // g: 0..11
        int lg = l0 + l;
        int ll = (k & 4) ? (LL - 1 - lg) : lg;
        int a = ll >> 8, b2 = (ll >> 4) & 15, c2 = ll & 15;
        int s;
        switch (k & 3) {
            case 0: s = ll;                        break;
            case 1: s = b2 * 256 + a * 16 + c2;    break;
            case 2: s = c2 * 256 + b2 * 16 + a;    break;
            default: s = a * 256 + c2 * 16 + b2;   break;
        }
        float4 v;
#pragma unroll
        for (int j = 0; j < 4; ++j) (&v.x)[j] = y_t[(g * 4 + j) * 68 + l];
        ((float4*)(y2 + (size_t)s * KD + k * DIN))[g] = v;
    }
}

// ---- Kernel 5: sum dirs + LayerNorm + gate + out_proj. Wave per s. ---------
__global__ __launch_bounds__(256) void k_final2(const float* __restrict__ y2,
                                                const float* __restrict__ z,
                                                const float* __restrict__ nw,
                                                const float* __restrict__ nb,
                                                const float* __restrict__ opw,
                                                float* __restrict__ out) {
    int wv = threadIdx.x >> 6, lane = threadIdx.x & 63;
    int s = blockIdx.x * 4 + wv;
    __shared__ float g[4][DIN];
    float val = 0.f;
    if (lane < DIN) {
        const float* yp = y2 + (size_t)s * KD + lane;
#pragma unroll
        for (int k = 0; k < KK; ++k) val += yp[k * DIN];
    }
    float m = val;
#pragma unroll
    for (int o = 32; o >= 1; o >>= 1) m += __shfl_xor(m, o, 64);
    m *= (1.f / 48.f);
    float dv = (lane < DIN) ? (val - m) : 0.f;
    float v2 = dv * dv;
#pragma unroll
    for (int o = 32; o >= 1; o >>= 1) v2 += __shfl_xor(v2, o, 64);
    v2 *= (1.f / 48.f);
    float inv = rsqrtf(v2 + 1e-5f);
    if (lane < DIN) {
        float yn = dv * inv * nw[lane] + nb[lane];
        float zz = z[s * DIN + lane];
        g[wv][lane] = yn * (zz / (1.f + __expf(-zz)));
    }
    __syncthreads();
    if (lane < DIN) {
        const float* wr = opw + lane * DIN;            // out_proj_w[c, e]
        float acc = 0.f;
#pragma unroll
        for (int e = 0; e < DIN; ++e) acc += g[wv][e] * wr[e];
        out[s * CC + lane] = acc;
    }
}

extern "C" void kernel_launch(void* const* d_in, const int* in_sizes, int n_in,
                              void* d_out, int out_size, void* d_ws, size_t ws_size,
                              hipStream_t stream) {
    const float* x      = (const float*)d_in[0];
    const float* ipw    = (const float*)d_in[1];
    const float* cw     = (const float*)d_in[2];
    const float* cb     = (const float*)d_in[3];
    const float* xpw    = (const float*)d_in[4];
    const float* dtw    = (const float*)d_in[5];
    const float* dtb    = (const float*)d_in[6];
    const float* A_logs = (const float*)d_in[7];
    const float* Ds     = (const float*)d_in[8];
    const float* nw     = (const float*)d_in[9];
    const float* nb     = (const float*)d_in[10];
    const float* opw    = (const float*)d_in[11];
    float* out = (float*)d_out;

    float* ws    = (float*)d_ws;
    float* xm    = ws;                                 // DIN*LL
    float* z     = xm + DIN * LL;                      // LL*DIN
    float* xc    = z + LL * DIN;                       // DIN*LL
    float* ud_g  = xc + DIN * LL;                      // 2*KD*LL (float2)
    float* BC    = ud_g + (size_t)2 * KD * LL;         // KK*LL*32
    float* y2    = BC + (size_t)KK * LL * 32;          // LL*KD (s-major)
    float* phf_g = y2 + (size_t)LL * KD;               // 2*KD*NCH*16 (float2)

    k_inproj<<<(LL * 96 + 255) / 256, 256, 0, stream>>>(x, ipw, xm, z);
    k_conv<<<(DIN * LL + 255) / 256, 256, 0, stream>>>(xm, cw, cb, xc);
    k_xscan1<<<KK * NCH, 768, 0, stream>>>(xc, xpw, dtw, dtb, A_logs,
                                           BC, ud_g, phf_g);
    k_scan3<<<KK * NCH, 768, 0, stream>>>(ud_g, BC, A_logs, Ds, phf_g, y2);
    k_final2<<<LL / 4, 256, 0, stream>>>(y2, z, nw, nb, opw, out);
}